// Round 14
// baseline (183.667 us; speedup 1.0000x reference)
//
#include <hip/hip_runtime.h>
#include <cmath>

#define NUM_POS 10
#define NEG 1000
#define COLS 1010          // NUM_POS + NEG
#define BATCH 4096
#define USERS 10001
#define ITEMS 10001
#define R_TOT (BATCH * NUM_POS)   // 40960
#define HSIZE (1 << 17)
#define GAMMA0 0.1f
#define EPSV 1e-10f

// u_new copy as dwords: out[i] = u[i-1] for i in [1, 100020001]
#define DW_TOTAL 100020001LL
#define DW_PER_BLOCK 2048                     // 8 dwords/thread
#define DW_BLOCKS ((DW_TOTAL + DW_PER_BLOCK - 1) / DW_PER_BLOCK)   // 48839
#define MEGA_BLOCKS (BATCH + DW_BLOCKS)       // 52935
#define SCAT_BLOCKS (R_TOT / 256)             // 160

__device__ __forceinline__ unsigned hash_key(int k) {
    return (((unsigned)k * 2654435761u) >> 13) & (HSIZE - 1);
}

// ---- mega kernel: bids [0,BATCH) = rows path; rest = dword copy path ----
__global__ void k_mega(const float* __restrict__ pred, const float* __restrict__ u,
                       float* __restrict__ out, float* __restrict__ rowM,
                       float* __restrict__ eRow, float* __restrict__ fRow,
                       float* __restrict__ mRow, int* __restrict__ hkey,
                       int* __restrict__ counter) {
    __shared__ float smem[1010];            // rows path only: 505 float2
    int t = threadIdx.x;

    if (blockIdx.x < BATCH) {
        // ---------------- rows path (R12 verbatim) ----------------
        int b = blockIdx.x;
        float2* lrow = (float2*)smem;
        __shared__ float smn[4], smx[4], sh[8];
        const float2* row2 = (const float2*)(pred + (size_t)b * COLS);  // 8B-aligned
        float mn = INFINITY, mx = -INFINITY;
        for (int i = t; i < 505; i += 256) {
            float2 v = row2[i];
            lrow[i] = v;
            if (i < 5) mn = fminf(mn, fminf(v.x, v.y));   // pos 0..9
            else       mx = fmaxf(mx, fmaxf(v.x, v.y));   // neg 10..1009
        }
        // init hash slice: 64 ints (16 int4) per block; hval contiguous after hkey
        if (t < 16)
            ((int4*)hkey)[b * 16 + t] = make_int4(-1, -1, -1, -1);
        if (b == 0 && t == 16) *counter = 0;

        int lane = t & 63, wid = t >> 6;
        for (int off = 32; off; off >>= 1) {
            mn = fminf(mn, __shfl_down(mn, off));
            mx = fmaxf(mx, __shfl_down(mx, off));
        }
        if (lane == 0) { smn[wid] = mn; smx[wid] = mx; }
        __syncthreads();
        mx = fmaxf(fmaxf(smx[0], smx[1]), fmaxf(smx[2], smx[3]));   // row neg-max
        if (t == 0) {
            mn = fminf(fminf(smn[0], smn[1]), fminf(smn[2], smn[3]));
            rowM[b] = mx - mn;    // row's max margin
            mRow[b] = mx;
        }
        // pass 2 from LDS with local shift
        float e = 0.f, f = 0.f;
        for (int i = 5 + t; i < 505; i += 256) {
            float2 v = lrow[i];
            float w0 = expf(v.x - mx), w1 = expf(v.y - mx);
            e += w0 + w1;
            f += v.x * w0 + v.y * w1;
        }
        for (int off = 32; off; off >>= 1) { e += __shfl_down(e, off); f += __shfl_down(f, off); }
        if (lane == 0) { sh[wid] = e; sh[4 + wid] = f; }
        __syncthreads();
        if (t == 0) {
            eRow[b] = (sh[0] + sh[1]) + (sh[2] + sh[3]);
            fRow[b] = (sh[4] + sh[5]) + (sh[6] + sh[7]);
        }
    } else {
        // ---- copy path: dword-aligned both sides, 8 dwords/thread, reg-staged ----
        long long c = blockIdx.x - BATCH;     // 0..DW_BLOCKS-1
        long long base = 1 + c * DW_PER_BLOCK + t;   // out dword index
        if (c < DW_BLOCKS - 1) {
            float v0 = __builtin_nontemporal_load(&u[base - 1]);
            float v1 = __builtin_nontemporal_load(&u[base - 1 + 256]);
            float v2 = __builtin_nontemporal_load(&u[base - 1 + 512]);
            float v3 = __builtin_nontemporal_load(&u[base - 1 + 768]);
            float v4 = __builtin_nontemporal_load(&u[base - 1 + 1024]);
            float v5 = __builtin_nontemporal_load(&u[base - 1 + 1280]);
            float v6 = __builtin_nontemporal_load(&u[base - 1 + 1536]);
            float v7 = __builtin_nontemporal_load(&u[base - 1 + 1792]);
            out[base]        = v0;
            out[base + 256]  = v1;
            out[base + 512]  = v2;
            out[base + 768]  = v3;
            out[base + 1024] = v4;
            out[base + 1280] = v5;
            out[base + 1536] = v6;
            out[base + 1792] = v7;
        } else {
#pragma unroll
            for (int j = 0; j < 8; ++j) {
                long long i = base + j * 256;
                if (i <= DW_TOTAL)
                    out[i] = __builtin_nontemporal_load(&u[i - 1]);
            }
        }
    }
}

// ---- kernel B: global M (per-block reduce of rowM), emit meanexp/sumS/keys + insert ----
__global__ void k_emit(const float* __restrict__ pred, const float* __restrict__ rowM,
                       const float* __restrict__ eRow, const float* __restrict__ fRow,
                       const float* __restrict__ mRow, const int* __restrict__ user_id,
                       const int* __restrict__ item_id, float* __restrict__ meanexp,
                       float* __restrict__ sumS, int* __restrict__ keys,
                       int* __restrict__ hkey, int* __restrict__ hval) {
    float mx = -INFINITY;
    for (int i = threadIdx.x; i < BATCH; i += 256) mx = fmaxf(mx, rowM[i]);
    __shared__ float smx[4];
    int lane = threadIdx.x & 63, wid = threadIdx.x >> 6;
    for (int off = 32; off; off >>= 1) mx = fmaxf(mx, __shfl_down(mx, off));
    if (lane == 0) smx[wid] = mx;
    __syncthreads();
    float M = fmaxf(fmaxf(smx[0], smx[1]), fmaxf(smx[2], smx[3]));  // global max margin

    int r = blockIdx.x * 256 + threadIdx.x;        // < 40960
    int b = r / NUM_POS, p = r - b * NUM_POS;
    float pos = pred[(size_t)b * COLS + p];
    float scale = expf(mRow[b] - M);
    float E = eRow[b] * scale, F = fRow[b] * scale;
    float s = expf(-pos);
    meanexp[r] = s * E * (1.0f / NEG);
    sumS[r]    = s * (F - pos * E);
    int key = user_id[b] * ITEMS + item_id[r];
    keys[r] = key;
    unsigned sl = hash_key(key);
    while (true) {
        int old = atomicCAS(&hkey[sl], -1, key);
        if (old == -1 || old == key) { atomicMax(&hval[sl], r); break; }
        sl = (sl + 1) & (HSIZE - 1);
    }
}

// ---- scatter winners + loss partials + deterministic last-block final reduce ----
__global__ void k_scatter(const float* __restrict__ u_in, const float* __restrict__ meanexp,
                          const float* __restrict__ sumS, const int* __restrict__ keys,
                          const int* __restrict__ hkey, const int* __restrict__ hval,
                          float* __restrict__ u_out, float* __restrict__ partial,
                          int* __restrict__ counter, float* __restrict__ out0) {
    int r = blockIdx.x * 256 + threadIdx.x;
    int k = keys[r];
    unsigned s = hash_key(k);
    while (hkey[s] != k) s = (s + 1) & (HSIZE - 1);
    int win = hval[s];                        // last duplicate index wins
    float uval = u_in[(size_t)k];
    float nv = (1.0f - GAMMA0) * uval + GAMMA0 * meanexp[win];
    if (win == r) u_out[(size_t)k] = nv;
    float contrib = sumS[r] / (nv + EPSV);

    __shared__ float sh[4];
    __shared__ int amLast;
    int lane = threadIdx.x & 63, wid = threadIdx.x >> 6;
    for (int off = 32; off; off >>= 1) contrib += __shfl_down(contrib, off);
    if (lane == 0) sh[wid] = contrib;
    __syncthreads();
    if (threadIdx.x == 0) {
        partial[blockIdx.x] = (sh[0] + sh[1]) + (sh[2] + sh[3]);
        __threadfence();
        int prev = atomicAdd(counter, 1);
        amLast = (prev == SCAT_BLOCKS - 1);
    }
    __syncthreads();
    if (amLast) {
        __threadfence();
        const volatile float* vp = (const volatile float*)partial;
        float v = (threadIdx.x < SCAT_BLOCKS) ? vp[threadIdx.x] : 0.0f;
        for (int off = 32; off; off >>= 1) v += __shfl_down(v, off);
        __shared__ float s2[4];
        if (lane == 0) s2[wid] = v;
        __syncthreads();
        if (threadIdx.x == 0)
            out0[0] = ((s2[0] + s2[1]) + (s2[2] + s2[3])) * (1.0f / BATCH);
    }
}

extern "C" void kernel_launch(void* const* d_in, const int* in_sizes, int n_in,
                              void* d_out, int out_size, void* d_ws, size_t ws_size,
                              hipStream_t stream) {
    const float* pred    = (const float*)d_in[0];   // (4096, 1010)
    const float* u       = (const float*)d_in[1];   // (10001, 10001)
    const int*   user_id = (const int*)d_in[2];     // (4096,)
    const int*   item_id = (const int*)d_in[3];     // (4096, 10) flat

    float* out = (float*)d_out;     // [0]=loss, [1..]=u_new

    char* w = (char*)d_ws;
    int*   hkey    = (int*)w;    w += HSIZE * sizeof(int);
    int*   hval    = (int*)w;    w += HSIZE * sizeof(int);   // contiguous after hkey
    int*   counter = (int*)w;    w += 64;
    float* rowM    = (float*)w;  w += BATCH * sizeof(float);
    float* eRow    = (float*)w;  w += BATCH * sizeof(float);
    float* fRow    = (float*)w;  w += BATCH * sizeof(float);
    float* mRow    = (float*)w;  w += BATCH * sizeof(float);
    float* meanexp = (float*)w;  w += R_TOT * sizeof(float);
    float* sumS    = (float*)w;  w += R_TOT * sizeof(float);
    int*   keys    = (int*)w;    w += R_TOT * sizeof(int);
    float* partial = (float*)w;  w += 256 * sizeof(float);

    k_mega<<<MEGA_BLOCKS, 256, 0, stream>>>(pred, u, out, rowM, eRow, fRow, mRow,
                                            hkey, counter);
    k_emit<<<SCAT_BLOCKS, 256, 0, stream>>>(pred, rowM, eRow, fRow, mRow,
                                            user_id, item_id, meanexp, sumS, keys,
                                            hkey, hval);
    k_scatter<<<SCAT_BLOCKS, 256, 0, stream>>>(u, meanexp, sumS, keys, hkey, hval,
                                               out + 1, partial, counter, out);
}

// Round 15
// 168.376 us; speedup vs baseline: 1.0908x; 1.0908x over previous
//
#include <hip/hip_runtime.h>
#include <cmath>

#define NUM_POS 10
#define NEG 1000
#define COLS 1010          // NUM_POS + NEG
#define BATCH 4096
#define USERS 10001
#define ITEMS 10001
#define R_TOT (BATCH * NUM_POS)   // 40960
#define HSIZE (1 << 17)
#define GAMMA0 0.1f
#define EPSV 1e-10f

#define N_U 100020001LL            // USERS*ITEMS elements in u
// out[0]=loss, out[1..N_U]=u_new.  out4[k]=out[4k..4k+3]; full quads k=1..25004999
#define KMAX 25005000LL
#define CPY_QUADS (KMAX - 1)                    // 25004999
#define CPY_BLOCKS ((CPY_QUADS + 255) / 256)    // 97676
#define MEGA_BLOCKS (BATCH + CPY_BLOCKS)        // 101772
#define SCAT_BLOCKS (R_TOT / 256)               // 160

typedef float __attribute__((ext_vector_type(4))) f32x4;

__device__ __forceinline__ unsigned hash_key(int k) {
    return (((unsigned)k * 2654435761u) >> 13) & (HSIZE - 1);
}

// ---- mega kernel: blocks [0,BATCH) = rows path; [BATCH,...) = NT copy path ----
__global__ void k_mega(const float* __restrict__ pred, const float* __restrict__ u,
                       float* __restrict__ out, float* __restrict__ rowM,
                       float* __restrict__ eRow, float* __restrict__ fRow,
                       float* __restrict__ mRow, int* __restrict__ hkey,
                       int* __restrict__ counter) {
    __shared__ float smem[1028];            // rows: 505 float2 (4040B); copy: 1028 floats
    int t = threadIdx.x;

    if (blockIdx.x < BATCH) {
        // ---------------- rows path ----------------
        int b = blockIdx.x;
        float2* lrow = (float2*)smem;
        __shared__ float smn[4], smx[4], sh[8];
        const float2* row2 = (const float2*)(pred + (size_t)b * COLS);  // 8B-aligned
        float mn = INFINITY, mx = -INFINITY;
        for (int i = t; i < 505; i += 256) {
            float2 v = row2[i];
            lrow[i] = v;
            if (i < 5) mn = fminf(mn, fminf(v.x, v.y));   // pos 0..9
            else       mx = fmaxf(mx, fmaxf(v.x, v.y));   // neg 10..1009
        }
        // init hash slice: 64 ints (16 int4) per block; hval contiguous after hkey
        if (t < 16)
            ((int4*)hkey)[b * 16 + t] = make_int4(-1, -1, -1, -1);
        if (b == 0 && t == 16) *counter = 0;

        int lane = t & 63, wid = t >> 6;
        for (int off = 32; off; off >>= 1) {
            mn = fminf(mn, __shfl_down(mn, off));
            mx = fmaxf(mx, __shfl_down(mx, off));
        }
        if (lane == 0) { smn[wid] = mn; smx[wid] = mx; }
        __syncthreads();
        mx = fmaxf(fmaxf(smx[0], smx[1]), fmaxf(smx[2], smx[3]));   // row neg-max
        if (t == 0) {
            mn = fminf(fminf(smn[0], smn[1]), fminf(smn[2], smn[3]));
            rowM[b] = mx - mn;    // row's max margin
            mRow[b] = mx;
        }
        // pass 2 from LDS with local shift
        float e = 0.f, f = 0.f;
        for (int i = 5 + t; i < 505; i += 256) {
            float2 v = lrow[i];
            float w0 = expf(v.x - mx), w1 = expf(v.y - mx);
            e += w0 + w1;
            f += v.x * w0 + v.y * w1;
        }
        for (int off = 32; off; off >>= 1) { e += __shfl_down(e, off); f += __shfl_down(f, off); }
        if (lane == 0) { sh[wid] = e; sh[4 + wid] = f; }
        __syncthreads();
        if (t == 0) {
            eRow[b] = (sh[0] + sh[1]) + (sh[2] + sh[3]);
            fRow[b] = (sh[4] + sh[5]) + (sh[6] + sh[7]);
        }
    } else {
        // -------- copy path (LDS realign + non-temporal load/store) --------
        float* lds = smem;
        const f32x4* __restrict__ u4 = (const f32x4*)u;
        f32x4* __restrict__ o4 = (f32x4*)out;
        long long K0 = 1 + (long long)(blockIdx.x - BATCH) * 256;
        long long k = K0 + t;
        int nq = (int)((KMAX - K0 < 256) ? (KMAX - K0) : 256);

        if (t < nq)
            ((f32x4*)lds)[t] = __builtin_nontemporal_load(&u4[k - 1]);
        if (t == 0)
            ((f32x4*)lds)[nq] = __builtin_nontemporal_load(&u4[K0 + nq - 1]);
        __syncthreads();
        if (t < nq) {
            f32x4 o;
            o.x = lds[4 * t + 3]; o.y = lds[4 * t + 4];
            o.z = lds[4 * t + 5]; o.w = lds[4 * t + 6];
            __builtin_nontemporal_store(o, &o4[k]);
        }
        if (blockIdx.x == BATCH && t == 0) {
            out[1] = u[0]; out[2] = u[1]; out[3] = u[2];
            out[100020000] = u[100019999];
            out[100020001] = u[100020000];
        }
    }
}

// ---- kernel B: global M (per-block reduce of rowM), emit meanexp/sumS/keys + insert ----
__global__ void k_emit(const float* __restrict__ pred, const float* __restrict__ rowM,
                       const float* __restrict__ eRow, const float* __restrict__ fRow,
                       const float* __restrict__ mRow, const int* __restrict__ user_id,
                       const int* __restrict__ item_id, float* __restrict__ meanexp,
                       float* __restrict__ sumS, int* __restrict__ keys,
                       int* __restrict__ hkey, int* __restrict__ hval) {
    float mx = -INFINITY;
    for (int i = threadIdx.x; i < BATCH; i += 256) mx = fmaxf(mx, rowM[i]);
    __shared__ float smx[4];
    int lane = threadIdx.x & 63, wid = threadIdx.x >> 6;
    for (int off = 32; off; off >>= 1) mx = fmaxf(mx, __shfl_down(mx, off));
    if (lane == 0) smx[wid] = mx;
    __syncthreads();
    float M = fmaxf(fmaxf(smx[0], smx[1]), fmaxf(smx[2], smx[3]));  // global max margin

    int r = blockIdx.x * 256 + threadIdx.x;        // < 40960
    int b = r / NUM_POS, p = r - b * NUM_POS;
    float pos = pred[(size_t)b * COLS + p];
    float scale = expf(mRow[b] - M);
    float E = eRow[b] * scale, F = fRow[b] * scale;
    float s = expf(-pos);
    meanexp[r] = s * E * (1.0f / NEG);
    sumS[r]    = s * (F - pos * E);
    int key = user_id[b] * ITEMS + item_id[r];
    keys[r] = key;
    unsigned sl = hash_key(key);
    while (true) {
        int old = atomicCAS(&hkey[sl], -1, key);
        if (old == -1 || old == key) { atomicMax(&hval[sl], r); break; }
        sl = (sl + 1) & (HSIZE - 1);
    }
}

// ---- scatter winners + loss partials + deterministic last-block final reduce ----
__global__ void k_scatter(const float* __restrict__ u_in, const float* __restrict__ meanexp,
                          const float* __restrict__ sumS, const int* __restrict__ keys,
                          const int* __restrict__ hkey, const int* __restrict__ hval,
                          float* __restrict__ u_out, float* __restrict__ partial,
                          int* __restrict__ counter, float* __restrict__ out0) {
    int r = blockIdx.x * 256 + threadIdx.x;
    int k = keys[r];
    unsigned s = hash_key(k);
    while (hkey[s] != k) s = (s + 1) & (HSIZE - 1);
    int win = hval[s];                        // last duplicate index wins
    float uval = u_in[(size_t)k];
    float nv = (1.0f - GAMMA0) * uval + GAMMA0 * meanexp[win];
    if (win == r) u_out[(size_t)k] = nv;
    float contrib = sumS[r] / (nv + EPSV);

    __shared__ float sh[4];
    __shared__ int amLast;
    int lane = threadIdx.x & 63, wid = threadIdx.x >> 6;
    for (int off = 32; off; off >>= 1) contrib += __shfl_down(contrib, off);
    if (lane == 0) sh[wid] = contrib;
    __syncthreads();
    if (threadIdx.x == 0) {
        partial[blockIdx.x] = (sh[0] + sh[1]) + (sh[2] + sh[3]);
        __threadfence();
        int prev = atomicAdd(counter, 1);
        amLast = (prev == SCAT_BLOCKS - 1);
    }
    __syncthreads();
    if (amLast) {
        __threadfence();
        const volatile float* vp = (const volatile float*)partial;
        float v = (threadIdx.x < SCAT_BLOCKS) ? vp[threadIdx.x] : 0.0f;
        for (int off = 32; off; off >>= 1) v += __shfl_down(v, off);
        __shared__ float s2[4];
        if (lane == 0) s2[wid] = v;
        __syncthreads();
        if (threadIdx.x == 0)
            out0[0] = ((s2[0] + s2[1]) + (s2[2] + s2[3])) * (1.0f / BATCH);
    }
}

extern "C" void kernel_launch(void* const* d_in, const int* in_sizes, int n_in,
                              void* d_out, int out_size, void* d_ws, size_t ws_size,
                              hipStream_t stream) {
    const float* pred    = (const float*)d_in[0];   // (4096, 1010)
    const float* u       = (const float*)d_in[1];   // (10001, 10001)
    const int*   user_id = (const int*)d_in[2];     // (4096,)
    const int*   item_id = (const int*)d_in[3];     // (4096, 10) flat

    float* out = (float*)d_out;     // [0]=loss, [1..]=u_new

    char* w = (char*)d_ws;
    int*   hkey    = (int*)w;    w += HSIZE * sizeof(int);
    int*   hval    = (int*)w;    w += HSIZE * sizeof(int);   // contiguous after hkey
    int*   counter = (int*)w;    w += 64;
    float* rowM    = (float*)w;  w += BATCH * sizeof(float);
    float* eRow    = (float*)w;  w += BATCH * sizeof(float);
    float* fRow    = (float*)w;  w += BATCH * sizeof(float);
    float* mRow    = (float*)w;  w += BATCH * sizeof(float);
    float* meanexp = (float*)w;  w += R_TOT * sizeof(float);
    float* sumS    = (float*)w;  w += R_TOT * sizeof(float);
    int*   keys    = (int*)w;    w += R_TOT * sizeof(int);
    float* partial = (float*)w;  w += 256 * sizeof(float);

    k_mega<<<MEGA_BLOCKS, 256, 0, stream>>>(pred, u, out, rowM, eRow, fRow, mRow,
                                            hkey, counter);
    k_emit<<<SCAT_BLOCKS, 256, 0, stream>>>(pred, rowM, eRow, fRow, mRow,
                                            user_id, item_id, meanexp, sumS, keys,
                                            hkey, hval);
    k_scatter<<<SCAT_BLOCKS, 256, 0, stream>>>(u, meanexp, sumS, keys, hkey, hval,
                                               out + 1, partial, counter, out);
}